// Round 7
// baseline (183.917 us; speedup 1.0000x reference)
//
#include <hip/hip_runtime.h>

// LTC cell: B=1024, I=128, N=256, 6 unfolds. Round 11: SIGMOID VIA LDS LUT.
// Busy-model fit across R0/R6-R9: VALU=2cyc, v_rcp=8, v_exp=16 per wave-instr
// -> transcendentals are 73% of the 132cyc/iter busy. Replace exp+rcp with a
// 256-entry linearly-interpolated sigma(t)=1/(1+2^t) table over t in [-16,16]
// (interp err ~9e-5; output tolerance 9.8e-3). Table is 32-WAY REPLICATED in
// LDS: tbl[idx][lane&31] float2{base,slope} -> lane l hits banks (2l,2l+1),
// pure 2-way aliasing = free (m136). 64KB table + 38KB working = 102KB/CU.
// Index transform pre-baked in pack: p.x=-8*sigma*log2e, p.y=8*sigma*mu*log2e
// +128, so u = fma(p.x,v,p.y) in [0,256) indexes the table directly.
// Everything else is the proven R0 structure (256 blocks x 1024 thr).

#define LOG2E 1.44269504088896340f

constexpr int Bn = 1024;
constexpr int In = 128;
constexpr int Nn = 256;
constexpr int UNFOLDS = 6;

#if __has_builtin(__builtin_amdgcn_exp2f)
#define EXP2F(x) __builtin_amdgcn_exp2f(x)
#else
#define EXP2F(x) __exp2f(x)
#endif
#if __has_builtin(__builtin_amdgcn_rcpf)
#define RCPF(x) __builtin_amdgcn_rcpf(x)
#else
#define RCPF(x) (1.0f / (x))
#endif
#if __has_builtin(__builtin_amdgcn_fmed3f)
#define FMED3(a, b, c) __builtin_amdgcn_fmed3f((a), (b), (c))
#else
#define FMED3(a, b, c) fminf(fmaxf((a), (b)), (c))
#endif
#if __has_builtin(__builtin_amdgcn_fractf)
#define FRACT(x) __builtin_amdgcn_fractf(x)
#else
#define FRACT(x) ((x) - floorf(x))
#endif

// ---------------------------------------------------------------------------
// Pack: Prec[i*N+n] = {-8*sigma*log2e, 8*sigma*mu*log2e + 128, W, W*erev}.
// Then u = fma(p.x, v, p.y) = 8*(B - A*v + 16) is the table coordinate
// (t = B - A*v in exp2 units, table spans t in [-16,16], h = 0.125).
// ---------------------------------------------------------------------------
__global__ __launch_bounds__(256) void pack_kernel(
    const float* __restrict__ mu, const float* __restrict__ sigma,
    const float* __restrict__ W, const float* __restrict__ erev,
    const float* __restrict__ smu, const float* __restrict__ ssigma,
    const float* __restrict__ sW, const float* __restrict__ serev,
    float4* __restrict__ Prec, float4* __restrict__ Psen) {
    int idx = blockIdx.x * 256 + threadIdx.x;
    if (idx < Nn * Nn) {
        float s = sigma[idx], m = mu[idx], w = W[idx], e = erev[idx];
        Prec[idx] = make_float4(-8.0f * s * LOG2E,
                                8.0f * s * m * LOG2E + 128.0f, w, w * e);
        return;
    }
    int j = idx - Nn * Nn;
    if (j < In * Nn) {
        float s = ssigma[j], m = smu[j], w = sW[j], e = serev[j];
        Psen[j] = make_float4(-8.0f * s * LOG2E,
                              8.0f * s * m * LOG2E + 128.0f, w, w * e);
    }
}

// ---------------------------------------------------------------------------
// Fused LTC kernel: sensory + 6 unfolds. Grid = 256 blocks x 1024 threads.
// Per-sigmoid: fma(arg) + med3(clamp) + cvt + fract + ds_read_b64 +
// interp-fma + 2 accum fma. Zero transcendentals in the hot loops.
// ---------------------------------------------------------------------------
__global__ __launch_bounds__(1024, 1) void ltc_fused_kernel(
    const float* __restrict__ inputs, const float* __restrict__ state,
    const float* __restrict__ input_w, const float* __restrict__ input_b,
    const float4* __restrict__ Psen, const float4* __restrict__ Prec,
    const float* __restrict__ vleak, const float* __restrict__ gleak,
    const float* __restrict__ cmt, float* __restrict__ out) {
    __shared__ float4 vt[Nn];            // [i] -> 4 batches packed, 4 KB
    __shared__ float2 part[4][4][Nn];    // [ih][bb][n], 32 KB
    __shared__ float4 xs[In];            // sensory x, [i] -> 4 batches, 2 KB
    __shared__ float2 tbl[256 * 32];     // 64 KB: [idx][replica] {base,slope}
    __shared__ float sig[257];           // 1 KB scratch for table build

    const int tid = threadIdx.x;
    const int b0 = blockIdx.x * 4;
    const int n = tid & 255;
    const int ih = tid >> 8;  // 0..3 : i-slice for compute, bb for reduce

    // ---- fill: v state + sensory x + sigma samples (all independent) ----
    float vp = state[(b0 + ih) * Nn + n];      // coalesced
    ((float*)vt)[n * 4 + ih] = vp;
    if (tid < 4 * In) {
        int i = tid & 127, bb = tid >> 7;      // bb in 0..3
        ((float*)xs)[i * 4 + bb] =
            inputs[(b0 + bb) * In + i] * input_w[i] + input_b[i];
    }
    if (tid < 257) {
        float t = (float)tid * 0.125f - 16.0f;
        sig[tid] = RCPF(1.0f + EXP2F(t));      // sigma at table knot
    }
    const float g = gleak[n], c = cmt[n];
    const float gvl = g * vleak[n];
    __syncthreads();

    // ---- build 32-way replicated {base, slope} table ----
#pragma unroll
    for (int e = tid; e < 256 * 32; e += 1024) {
        int j = e >> 5;
        tbl[e] = make_float2(sig[j], sig[j + 1] - sig[j]);
    }
    __syncthreads();

    const float2* __restrict__ tlane = tbl + (tid & 31);  // lane's replica

    // ---- sensory sums (i = 0..127, slice 32 per ih) ----
    float sens_n, sens_d;
    {
        float num[4] = {0.f, 0.f, 0.f, 0.f};
        float den[4] = {0.f, 0.f, 0.f, 0.f};
        const float4* __restrict__ pp = Psen + n;
#pragma unroll 8
        for (int i = ih * 32; i < ih * 32 + 32; ++i) {
            float4 p = pp[i * Nn];   // coalesced dwordx4
            float4 v = xs[i];        // b128 broadcast (ih wave-uniform)
#pragma unroll
            for (int bb = 0; bb < 4; ++bb) {
                float vb = (bb == 0) ? v.x : (bb == 1) ? v.y : (bb == 2) ? v.z : v.w;
                float u = FMED3(fmaf(p.x, vb, p.y), 0.0f, 254.99f);
                int idx = (int)u;
                float f = FRACT(u);
                float2 t2 = tlane[idx << 5];         // ds_read_b64, 2-way ok
                float r = fmaf(t2.y, f, t2.x);
                den[bb] += p.z * r;
                num[bb] += p.w * r;
            }
        }
#pragma unroll
        for (int bb = 0; bb < 4; ++bb)
            part[ih][bb][n] = make_float2(num[bb], den[bb]);
        __syncthreads();
        float wn = 0.f, wd = 0.f;
#pragma unroll
        for (int s = 0; s < 4; ++s) {
            float2 v = part[s][ih][n];  // this thread's bb == ih
            wn += v.x;
            wd += v.y;
        }
        sens_n = wn;
        sens_d = wd;
    }

    // ---- 6 unfolds ----
    const float4* __restrict__ pp = Prec + n;
    for (int s = 0; s < UNFOLDS; ++s) {
        __syncthreads();  // vt writes from prev step visible; part reusable
        float num[4] = {0.f, 0.f, 0.f, 0.f};
        float den[4] = {0.f, 0.f, 0.f, 0.f};
#pragma unroll 8
        for (int i = ih * 64; i < ih * 64 + 64; ++i) {
            float4 p = pp[i * Nn];   // coalesced dwordx4 (L2-resident stream)
            float4 v = vt[i];        // b128 broadcast
#pragma unroll
            for (int bb = 0; bb < 4; ++bb) {
                float vb = (bb == 0) ? v.x : (bb == 1) ? v.y : (bb == 2) ? v.z : v.w;
                float u = FMED3(fmaf(p.x, vb, p.y), 0.0f, 254.99f);
                int idx = (int)u;
                float f = FRACT(u);
                float2 t2 = tlane[idx << 5];         // ds_read_b64, 2-way ok
                float r = fmaf(t2.y, f, t2.x);
                den[bb] += p.z * r;
                num[bb] += p.w * r;
            }
        }
#pragma unroll
        for (int bb = 0; bb < 4; ++bb)
            part[ih][bb][n] = make_float2(num[bb], den[bb]);
        __syncthreads();
        // reduce for this thread's (bb=ih, n)
        float wn = sens_n, wd = sens_d;
#pragma unroll
        for (int s2 = 0; s2 < 4; ++s2) {
            float2 v = part[s2][ih][n];
            wn += v.x;
            wd += v.y;
        }
        float res = (c * vp + gvl + wn) * RCPF(c + g + wd);
        vp = res;
        if (s == UNFOLDS - 1)
            out[(b0 + ih) * Nn + n] = res;       // coalesced final store
        else
            ((float*)vt)[n * 4 + ih] = res;
    }
}

// ---------------------------------------------------------------------------
extern "C" void kernel_launch(void* const* d_in, const int* in_sizes, int n_in,
                              void* d_out, int out_size, void* d_ws, size_t ws_size,
                              hipStream_t stream) {
    const float* inputs   = (const float*)d_in[0];
    const float* state    = (const float*)d_in[1];
    const float* input_w  = (const float*)d_in[2];
    const float* input_b  = (const float*)d_in[3];
    const float* smu      = (const float*)d_in[4];
    const float* ssigma   = (const float*)d_in[5];
    const float* sW       = (const float*)d_in[6];
    const float* serev    = (const float*)d_in[7];
    const float* mu       = (const float*)d_in[8];
    const float* sigma    = (const float*)d_in[9];
    const float* W        = (const float*)d_in[10];
    const float* erev     = (const float*)d_in[11];
    const float* vleak    = (const float*)d_in[12];
    const float* gleak    = (const float*)d_in[13];
    const float* cmt      = (const float*)d_in[14];
    float* out = (float*)d_out;

    // Workspace: Prec 1 MiB | Psen 512 KiB
    char* ws = (char*)d_ws;
    float4* Prec = (float4*)ws;
    float4* Psen = (float4*)(ws + (1u << 20));

    pack_kernel<<<(Nn * Nn + In * Nn + 255) / 256, 256, 0, stream>>>(
        mu, sigma, W, erev, smu, ssigma, sW, serev, Prec, Psen);

    ltc_fused_kernel<<<Bn / 4, 1024, 0, stream>>>(
        inputs, state, input_w, input_b, Psen, Prec, vleak, gleak, cmt, out);
}

// Round 8
// 172.529 us; speedup vs baseline: 1.0660x; 1.0660x over previous
//
#include <hip/hip_runtime.h>

// LTC cell: B=1024, I=128, N=256, 6 unfolds. Round 12: R0 + PACKED FP32.
// Issue-model refit across ALL six kernels (tight, +/-5%): every VALU instr
// ~4 SIMD-cyc of issue, transcendentals +4 extra. R11's LUT was null because
// it swapped 8 trans-extras for 8 address/interp instrs. Lever = instruction
// COUNT. MI355X's 157 TF fp32 peak is the v_pk_*_f32 PACKED rate (VOP3P,
// gfx90a+); this kernel was 100% scalar. Packing the sigmoid quad:
//   2 pk_fma (args, op_sel splats of the loaded (A,B) pair)
// + 4 v_exp + 2 pk_add (1+e) + 4 v_rcp
// + 4 pk_fma (accum {den,num} per batch vs the natural (W,WE) pair)
// = 16 instr + 8 trans = ~96 cyc/iter vs R0's 24+8 = 128. Bit-identical math.
// Everything else (grid 256x1024, lane map, part[] reduce, barriers, memory
// pattern) is exactly the proven R0 structure (113.7 us @ 77% busy).

#define LOG2E 1.44269504088896340f

constexpr int Bn = 1024;
constexpr int In = 128;
constexpr int Nn = 256;
constexpr int UNFOLDS = 6;

typedef float v2f __attribute__((ext_vector_type(2)));

#if __has_builtin(__builtin_amdgcn_exp2f)
#define EXP2F(x) __builtin_amdgcn_exp2f(x)
#else
#define EXP2F(x) __exp2f(x)
#endif
#if __has_builtin(__builtin_amdgcn_rcpf)
#define RCPF(x) __builtin_amdgcn_rcpf(x)
#else
#define RCPF(x) (1.0f / (x))
#endif

// ---------------------------------------------------------------------------
// Pack: Prec[i*N+n] = {sigma*log2e, sigma*mu*log2e, W, W*erev}; same for Psen.
// sigmoid(sigma*(v-mu)) = 1/(1 + exp2(B - A*v)), A=sigma*log2e, B=sigma*mu*log2e.
// ---------------------------------------------------------------------------
__global__ __launch_bounds__(256) void pack_kernel(
    const float* __restrict__ mu, const float* __restrict__ sigma,
    const float* __restrict__ W, const float* __restrict__ erev,
    const float* __restrict__ smu, const float* __restrict__ ssigma,
    const float* __restrict__ sW, const float* __restrict__ serev,
    float4* __restrict__ Prec, float4* __restrict__ Psen) {
    int idx = blockIdx.x * 256 + threadIdx.x;
    if (idx < Nn * Nn) {
        float s = sigma[idx], m = mu[idx], w = W[idx], e = erev[idx];
        Prec[idx] = make_float4(s * LOG2E, s * m * LOG2E, w, w * e);
        return;
    }
    int j = idx - Nn * Nn;
    if (j < In * Nn) {
        float s = ssigma[j], m = smu[j], w = sW[j], e = serev[j];
        Psen[j] = make_float4(s * LOG2E, s * m * LOG2E, w, w * e);
    }
}

// ---------------------------------------------------------------------------
// Fused LTC kernel: sensory + 6 unfolds. Grid = 256 blocks x 1024 threads.
// Inner quad in packed fp32: acc_b = {den_b, num_b} accumulated with one
// v_pk_fma against the (W, W*erev) register pair; args/1+e packed batch-pair.
// ---------------------------------------------------------------------------
__global__ __launch_bounds__(1024, 1) void ltc_fused_kernel(
    const float* __restrict__ inputs, const float* __restrict__ state,
    const float* __restrict__ input_w, const float* __restrict__ input_b,
    const float4* __restrict__ Psen, const float4* __restrict__ Prec,
    const float* __restrict__ vleak, const float* __restrict__ gleak,
    const float* __restrict__ cmt, float* __restrict__ out) {
    __shared__ float4 vt[Nn];            // [i] -> 4 batches packed, 4 KB
    __shared__ float2 part[4][4][Nn];    // [ih][bb][n], 32 KB
    __shared__ float4 xs[In];            // sensory x, [i] -> 4 batches, 2 KB

    const int tid = threadIdx.x;
    const int b0 = blockIdx.x * 4;
    const int n = tid & 255;
    const int ih = tid >> 8;  // 0..3 : i-slice for compute, bb for reduce

    // ---- fill: v state (this thread's (bb=ih, n) value) + sensory x ----
    float vp = state[(b0 + ih) * Nn + n];      // coalesced
    ((float*)vt)[n * 4 + ih] = vp;
    if (tid < 4 * In) {
        int i = tid & 127, bb = tid >> 7;      // bb in 0..3
        ((float*)xs)[i * 4 + bb] =
            inputs[(b0 + bb) * In + i] * input_w[i] + input_b[i];
    }
    // leak params for this thread's n (wavefront-coalesced loads)
    const float g = gleak[n], c = cmt[n];
    const float gvl = g * vleak[n];
    __syncthreads();

    // ---- sensory sums (i = 0..127, slice 32 per ih) ----
    float sens_n, sens_d;
    {
        v2f acc0 = {0.f, 0.f}, acc1 = {0.f, 0.f};   // {den,num} per batch
        v2f acc2 = {0.f, 0.f}, acc3 = {0.f, 0.f};
        const float4* __restrict__ pp = Psen + n;
#pragma unroll 8
        for (int i = ih * 32; i < ih * 32 + 32; ++i) {
            float4 p = pp[i * Nn];   // coalesced dwordx4
            float4 v = xs[i];        // b128 broadcast (ih wave-uniform)
            v2f AA = {p.x, p.x};     // op_sel splat of (p.x,p.y) pair
            v2f BB = {p.y, p.y};
            v2f WW = {p.z, p.w};     // natural adjacent pair
            v2f u01 = __builtin_elementwise_fma(-AA, (v2f){v.x, v.y}, BB);
            v2f u23 = __builtin_elementwise_fma(-AA, (v2f){v.z, v.w}, BB);
            v2f a01 = (v2f){EXP2F(u01.x), EXP2F(u01.y)} + 1.0f;  // pk_add
            v2f a23 = (v2f){EXP2F(u23.x), EXP2F(u23.y)} + 1.0f;
            float r0 = RCPF(a01.x), r1 = RCPF(a01.y);
            float r2 = RCPF(a23.x), r3 = RCPF(a23.y);
            acc0 = __builtin_elementwise_fma(WW, (v2f){r0, r0}, acc0);
            acc1 = __builtin_elementwise_fma(WW, (v2f){r1, r1}, acc1);
            acc2 = __builtin_elementwise_fma(WW, (v2f){r2, r2}, acc2);
            acc3 = __builtin_elementwise_fma(WW, (v2f){r3, r3}, acc3);
        }
        part[ih][0][n] = make_float2(acc0.y, acc0.x);  // {num, den}
        part[ih][1][n] = make_float2(acc1.y, acc1.x);
        part[ih][2][n] = make_float2(acc2.y, acc2.x);
        part[ih][3][n] = make_float2(acc3.y, acc3.x);
        __syncthreads();
        float wn = 0.f, wd = 0.f;
#pragma unroll
        for (int s = 0; s < 4; ++s) {
            float2 v = part[s][ih][n];  // this thread's bb == ih
            wn += v.x;
            wd += v.y;
        }
        sens_n = wn;
        sens_d = wd;
    }

    // ---- 6 unfolds ----
    const float4* __restrict__ pp = Prec + n;
    for (int s = 0; s < UNFOLDS; ++s) {
        __syncthreads();  // vt writes from prev step visible; part reusable
        v2f acc0 = {0.f, 0.f}, acc1 = {0.f, 0.f};
        v2f acc2 = {0.f, 0.f}, acc3 = {0.f, 0.f};
#pragma unroll 8
        for (int i = ih * 64; i < ih * 64 + 64; ++i) {
            float4 p = pp[i * Nn];   // coalesced dwordx4 (L2-resident stream)
            float4 v = vt[i];        // b128 broadcast
            v2f AA = {p.x, p.x};
            v2f BB = {p.y, p.y};
            v2f WW = {p.z, p.w};
            v2f u01 = __builtin_elementwise_fma(-AA, (v2f){v.x, v.y}, BB);
            v2f u23 = __builtin_elementwise_fma(-AA, (v2f){v.z, v.w}, BB);
            v2f a01 = (v2f){EXP2F(u01.x), EXP2F(u01.y)} + 1.0f;
            v2f a23 = (v2f){EXP2F(u23.x), EXP2F(u23.y)} + 1.0f;
            float r0 = RCPF(a01.x), r1 = RCPF(a01.y);
            float r2 = RCPF(a23.x), r3 = RCPF(a23.y);
            acc0 = __builtin_elementwise_fma(WW, (v2f){r0, r0}, acc0);
            acc1 = __builtin_elementwise_fma(WW, (v2f){r1, r1}, acc1);
            acc2 = __builtin_elementwise_fma(WW, (v2f){r2, r2}, acc2);
            acc3 = __builtin_elementwise_fma(WW, (v2f){r3, r3}, acc3);
        }
        part[ih][0][n] = make_float2(acc0.y, acc0.x);
        part[ih][1][n] = make_float2(acc1.y, acc1.x);
        part[ih][2][n] = make_float2(acc2.y, acc2.x);
        part[ih][3][n] = make_float2(acc3.y, acc3.x);
        __syncthreads();
        // reduce for this thread's (bb=ih, n)
        float wn = sens_n, wd = sens_d;
#pragma unroll
        for (int s2 = 0; s2 < 4; ++s2) {
            float2 v = part[s2][ih][n];
            wn += v.x;
            wd += v.y;
        }
        float res = (c * vp + gvl + wn) * RCPF(c + g + wd);
        vp = res;
        if (s == UNFOLDS - 1)
            out[(b0 + ih) * Nn + n] = res;       // coalesced final store
        else
            ((float*)vt)[n * 4 + ih] = res;
    }
}

// ---------------------------------------------------------------------------
extern "C" void kernel_launch(void* const* d_in, const int* in_sizes, int n_in,
                              void* d_out, int out_size, void* d_ws, size_t ws_size,
                              hipStream_t stream) {
    const float* inputs   = (const float*)d_in[0];
    const float* state    = (const float*)d_in[1];
    const float* input_w  = (const float*)d_in[2];
    const float* input_b  = (const float*)d_in[3];
    const float* smu      = (const float*)d_in[4];
    const float* ssigma   = (const float*)d_in[5];
    const float* sW       = (const float*)d_in[6];
    const float* serev    = (const float*)d_in[7];
    const float* mu       = (const float*)d_in[8];
    const float* sigma    = (const float*)d_in[9];
    const float* W        = (const float*)d_in[10];
    const float* erev     = (const float*)d_in[11];
    const float* vleak    = (const float*)d_in[12];
    const float* gleak    = (const float*)d_in[13];
    const float* cmt      = (const float*)d_in[14];
    float* out = (float*)d_out;

    // Workspace: Prec 1 MiB | Psen 512 KiB
    char* ws = (char*)d_ws;
    float4* Prec = (float4*)ws;
    float4* Psen = (float4*)(ws + (1u << 20));

    pack_kernel<<<(Nn * Nn + In * Nn + 255) / 256, 256, 0, stream>>>(
        mu, sigma, W, erev, smu, ssigma, sW, serev, Prec, Psen);

    ltc_fused_kernel<<<Bn / 4, 1024, 0, stream>>>(
        inputs, state, input_w, input_b, Psen, Prec, vleak, gleak, cmt, out);
}